// Round 13
// baseline (690.305 us; speedup 1.0000x reference)
//
#include <hip/hip_runtime.h>

typedef unsigned short u16;
typedef __attribute__((ext_vector_type(8))) short s16x8;
typedef __attribute__((ext_vector_type(8))) unsigned short u16x8;
typedef __attribute__((ext_vector_type(4))) float f32x4;

#define AS1 __attribute__((address_space(1)))
#define AS3 __attribute__((address_space(3)))

__device__ __forceinline__ float bf2f(u16 u) {
  union { unsigned u; float f; } x; x.u = ((unsigned)u) << 16; return x.f;
}
__device__ __forceinline__ u16 f2bf(float f) {
  union { float f; unsigned u; } x; x.f = f;
  unsigned r = x.u + 0x7fffu + ((x.u >> 16) & 1u);
  return (u16)(r >> 16);
}
__device__ __forceinline__ float celu_f(float x) {
  return x > 0.f ? x : 1.3f * expm1f(x * (1.0f / 1.3f));
}

// ---------------------------------------------------------------------------
// fp32 -> bf16 elementwise convert (HBM-bound). n multiple of 8.
// ---------------------------------------------------------------------------
__global__ __launch_bounds__(256) void convert_bf16(
    const float* __restrict__ X, u16* __restrict__ Y, long n)
{
  long i = ((long)blockIdx.x * 256 + threadIdx.x) * 8;
  const long stride = (long)gridDim.x * 256 * 8;
  for (; i < n; i += stride) {
    f32x4 a = *(const f32x4*)(X + i);
    f32x4 b = *(const f32x4*)(X + i + 4);
    u16x8 t;
#pragma unroll
    for (int e = 0; e < 4; ++e) { t[e] = f2bf(a[e]); t[4 + e] = f2bf(b[e]); }
    *(u16x8*)(Y + i) = t;
  }
}

// ---------------------------------------------------------------------------
// Transpose + fp32->bf16 for the two 1024x1024 weights in ONE dispatch:
// by<32 -> Wk, else Wv2.  grid(32,64), block(32,8).
// ---------------------------------------------------------------------------
__global__ __launch_bounds__(256) void transpose2_bf16(
    const float* __restrict__ W0, u16* __restrict__ WT0,
    const float* __restrict__ W1, u16* __restrict__ WT1)
{
  __shared__ float tile[32][33];
  const int bx = blockIdx.x;
  const int sel = blockIdx.y >> 5;
  const int by = blockIdx.y & 31;
  const float* W = sel ? W1 : W0;
  u16* WT = sel ? WT1 : WT0;
  const int tx = threadIdx.x, ty = threadIdx.y;
#pragma unroll
  for (int i = ty; i < 32; i += 8)
    tile[i][tx] = W[(by * 32 + i) * 1024 + bx * 32 + tx];
  __syncthreads();
#pragma unroll
  for (int i = ty; i < 32; i += 8)
    WT[(bx * 32 + i) * 1024 + by * 32 + tx] = f2bf(tile[tx][i]);
}

// small transpose for Wb (HDxM1 = 128x64)
__global__ __launch_bounds__(256) void transpose_bf16(
    const float* __restrict__ W, u16* __restrict__ WT, int R, int C)
{
  __shared__ float tile[32][33];
  const int bx = blockIdx.x, by = blockIdx.y;
  const int tx = threadIdx.x, ty = threadIdx.y;
#pragma unroll
  for (int i = ty; i < 32; i += 8)
    tile[i][tx] = W[(by * 32 + i) * C + bx * 32 + tx];
  __syncthreads();
#pragma unroll
  for (int i = ty; i < 32; i += 8)
    WT[(bx * 32 + i) * R + by * 32 + tx] = f2bf(tile[tx][i]);
}

// ---------------------------------------------------------------------------
// q AND v1 branch in one dispatch (fp32): out = groupnorm(celu(X@W + b)).
// grid 1024: bid<512 -> (query path), else (value1 path).
// ---------------------------------------------------------------------------
__global__ __launch_bounds__(128) void branch_small2(
    const float* __restrict__ X0, const float* __restrict__ W0,
    const float* __restrict__ b0, const float* __restrict__ g0,
    const float* __restrict__ be0, float* __restrict__ o0,
    const float* __restrict__ X1, const float* __restrict__ W1,
    const float* __restrict__ b1, const float* __restrict__ g1,
    const float* __restrict__ be1, float* __restrict__ o1)
{
  const int bid = blockIdx.x;
  const int sel = bid >> 9;
  const float* X = sel ? X1 : X0;  const float* W = sel ? W1 : W0;
  const float* bias = sel ? b1 : b0; const float* gamma = sel ? g1 : g0;
  const float* beta = sel ? be1 : be0; float* out = sel ? o1 : o0;
  const int b = (bid & 511) >> 3, grp = bid & 7;
  const int t = threadIdx.x;
  __shared__ float xs[1024];
  __shared__ float r1[2], r2[2];
  for (int i = t; i < 1024; i += 128) xs[i] = X[b * 1024 + i];
  __syncthreads();
  const int col = grp * 128 + t;
  const float* wp = W + col;
  float a0 = 0.f, a1 = 0.f, a2 = 0.f, a3 = 0.f;
  for (int k = 0; k < 1024; k += 4) {
    a0 += xs[k]     * wp[(k)     * 1024];
    a1 += xs[k + 1] * wp[(k + 1) * 1024];
    a2 += xs[k + 2] * wp[(k + 2) * 1024];
    a3 += xs[k + 3] * wp[(k + 3) * 1024];
  }
  float x = (a0 + a1) + (a2 + a3) + bias[col];
  float c = celu_f(x);
  float s1 = c, s2 = c * c;
#pragma unroll
  for (int m = 1; m < 64; m <<= 1) { s1 += __shfl_xor(s1, m); s2 += __shfl_xor(s2, m); }
  const int w = t >> 6;
  if ((t & 63) == 0) { r1[w] = s1; r2[w] = s2; }
  __syncthreads();
  float t1 = r1[0] + r1[1], t2 = r2[0] + r2[1];
  float mean = t1 * 0.0078125f;
  float var  = t2 * 0.0078125f - mean * mean;
  float inv  = rsqrtf(var + 1e-5f);
  out[b * 1024 + col] = (c - mean) * inv * gamma[col] + beta[col];
}

// ---------------------------------------------------------------------------
// 256x256-tile, BK=64, 8-wave GEMM — T3 minimum 2-phase sync (guide recipe):
// per K-tile: STAGE(nslot, t+1) [8 gload_lds] FIRST, then 4 read-clusters
// {ds_read_b128 x8/x4; lgkmcnt(0)+sched_barrier; 16 MFMA} with NO interior
// barriers (frag pressure stays ~cluster-local), then ONE __syncthreads()
// (full vm+lgkm drain: publishes slot t+1, protects slot t for overwrite at
// t+1).  Staged loads get a full 64-MFMA tile (~1300+ cyc) of cover before
// the drain.  1 barrier/K-tile vs round-7's 8.  Everything else (LDS layout,
// T2 swizzle both-sides, XCD swizzle, spill-proof LDS-staged GN epilogue)
// byte-identical to the round-7/8/12 verified kernel.
// grid 1024, block 512, 1 block/CU.
// ---------------------------------------------------------------------------
__global__ void
__attribute__((amdgpu_flat_work_group_size(512, 512), amdgpu_waves_per_eu(2, 2)))
gemm256p2(
    const u16* __restrict__ A16, const u16* __restrict__ WT,
    const float* __restrict__ bias, const float* __restrict__ gamma,
    const float* __restrict__ beta, u16* __restrict__ Cout)
{
  __shared__ __align__(16) char lds_raw[143360];

  const int tid  = threadIdx.x;
  const int lane = tid & 63;
  const int w    = tid >> 6;
  const int wr   = w >> 2, wc = w & 3;
  const int lg   = lane >> 4, ln = lane & 15;

  const int bid = blockIdx.x;
  const int v   = (bid & 7) * 128 + (bid >> 3);
  const int mt  = v >> 2, nt = v & 3;

  const int trow = tid >> 3;
  const int gsw  = ((tid & 7) ^ (trow & 7)) * 8;
  const u16* aS00 = A16 + (long)(mt * 256 +   0 +  0 + trow) * 1024 + gsw;
  const u16* aS01 = A16 + (long)(mt * 256 +   0 + 64 + trow) * 1024 + gsw;
  const u16* aS10 = A16 + (long)(mt * 256 + 128 +  0 + trow) * 1024 + gsw;
  const u16* aS11 = A16 + (long)(mt * 256 + 128 + 64 + trow) * 1024 + gsw;
  const u16* bS0  = WT  + (long)(nt * 256 +   0 + trow) * 1024 + gsw;
  const u16* bS1  = WT  + (long)(nt * 256 +  64 + trow) * 1024 + gsw;
  const u16* bS2  = WT  + (long)(nt * 256 + 128 + trow) * 1024 + gsw;
  const u16* bS3  = WT  + (long)(nt * 256 + 192 + trow) * 1024 + gsw;

#define AQOFF(wr2, h, sl) ((((wr2) * 2 + (h)) * 2 + (sl)) * 8192)
#define BOFF(sl)          (65536 + (sl) * 32768)

#define STAGE_ALL(sl, kt)                                                       \
  { __builtin_amdgcn_global_load_lds((const AS1 void*)(bS0 + (kt) * 64),        \
        (AS3 void*)(lds_raw + BOFF(sl) +     0 + w * 1024), 16, 0, 0);          \
    __builtin_amdgcn_global_load_lds((const AS1 void*)(bS1 + (kt) * 64),        \
        (AS3 void*)(lds_raw + BOFF(sl) +  8192 + w * 1024), 16, 0, 0);          \
    __builtin_amdgcn_global_load_lds((const AS1 void*)(bS2 + (kt) * 64),        \
        (AS3 void*)(lds_raw + BOFF(sl) + 16384 + w * 1024), 16, 0, 0);          \
    __builtin_amdgcn_global_load_lds((const AS1 void*)(bS3 + (kt) * 64),        \
        (AS3 void*)(lds_raw + BOFF(sl) + 24576 + w * 1024), 16, 0, 0);          \
    __builtin_amdgcn_global_load_lds((const AS1 void*)(aS00 + (kt) * 64),       \
        (AS3 void*)(lds_raw + AQOFF(0, 0, sl) + w * 1024), 16, 0, 0);           \
    __builtin_amdgcn_global_load_lds((const AS1 void*)(aS10 + (kt) * 64),       \
        (AS3 void*)(lds_raw + AQOFF(1, 0, sl) + w * 1024), 16, 0, 0);           \
    __builtin_amdgcn_global_load_lds((const AS1 void*)(aS01 + (kt) * 64),       \
        (AS3 void*)(lds_raw + AQOFF(0, 1, sl) + w * 1024), 16, 0, 0);           \
    __builtin_amdgcn_global_load_lds((const AS1 void*)(aS11 + (kt) * 64),       \
        (AS3 void*)(lds_raw + AQOFF(1, 1, sl) + w * 1024), 16, 0, 0); }

  int aoff0[4], aoff1[4], boff0[4], boff1[4];
#pragma unroll
  for (int la = 0; la < 4; ++la) {
    int rq = la * 16 + ln;
    aoff0[la] = rq * 128 + (((0 * 4 + lg) ^ (ln & 7)) * 16);
    aoff1[la] = rq * 128 + (((1 * 4 + lg) ^ (ln & 7)) * 16);
  }
#pragma unroll
  for (int j = 0; j < 4; ++j) {
    int nl = wc * 64 + j * 16 + ln;
    boff0[j] = nl * 128 + (((0 * 4 + lg) ^ (ln & 7)) * 16);
    boff1[j] = nl * 128 + (((1 * 4 + lg) ^ (ln & 7)) * 16);
  }

  f32x4 acc[8][4] = {};

#define MFMA_SET(IB, BF)                                                        \
    _Pragma("unroll")                                                           \
    for (int la = 0; la < 4; ++la)                                              \
      _Pragma("unroll")                                                         \
      for (int j = 0; j < 4; ++j)                                               \
        acc[(IB) + la][j] = __builtin_amdgcn_mfma_f32_16x16x32_bf16(            \
            afv[la], BF[j], acc[(IB) + la][j], 0, 0, 0);

#define KITER(T, STG)                                                           \
  {                                                                             \
    const int slot = (T) & 1, nslot = slot ^ 1;                                 \
    const char* aqb0 = lds_raw + AQOFF(wr, 0, slot);                            \
    const char* aqb1 = lds_raw + AQOFF(wr, 1, slot);                            \
    const char* bqb  = lds_raw + BOFF(slot);                                    \
    s16x8 bfr[4], afv[4];                                                       \
    if (STG) STAGE_ALL(nslot, (T) + 1);                                         \
    /* cluster 1: low x ks0 */                                                  \
    _Pragma("unroll")                                                           \
    for (int la = 0; la < 4; ++la) afv[la] = *(const s16x8*)(aqb0 + aoff0[la]); \
    _Pragma("unroll")                                                           \
    for (int j = 0; j < 4; ++j) bfr[j] = *(const s16x8*)(bqb + boff0[j]);       \
    asm volatile("s_waitcnt lgkmcnt(0)" ::);                                    \
    __builtin_amdgcn_sched_barrier(0);                                          \
    __builtin_amdgcn_s_setprio(1);                                              \
    MFMA_SET(0, bfr)                                                            \
    __builtin_amdgcn_s_setprio(0);                                              \
    /* cluster 2: up x ks0 */                                                   \
    _Pragma("unroll")                                                           \
    for (int la = 0; la < 4; ++la) afv[la] = *(const s16x8*)(aqb1 + aoff0[la]); \
    asm volatile("s_waitcnt lgkmcnt(0)" ::);                                    \
    __builtin_amdgcn_sched_barrier(0);                                          \
    __builtin_amdgcn_s_setprio(1);                                              \
    MFMA_SET(4, bfr)                                                            \
    __builtin_amdgcn_s_setprio(0);                                              \
    /* cluster 3: low x ks1 */                                                  \
    _Pragma("unroll")                                                           \
    for (int la = 0; la < 4; ++la) afv[la] = *(const s16x8*)(aqb0 + aoff1[la]); \
    _Pragma("unroll")                                                           \
    for (int j = 0; j < 4; ++j) bfr[j] = *(const s16x8*)(bqb + boff1[j]);       \
    asm volatile("s_waitcnt lgkmcnt(0)" ::);                                    \
    __builtin_amdgcn_sched_barrier(0);                                          \
    __builtin_amdgcn_s_setprio(1);                                              \
    MFMA_SET(0, bfr)                                                            \
    __builtin_amdgcn_s_setprio(0);                                              \
    /* cluster 4: up x ks1 */                                                   \
    _Pragma("unroll")                                                           \
    for (int la = 0; la < 4; ++la) afv[la] = *(const s16x8*)(aqb1 + aoff1[la]); \
    asm volatile("s_waitcnt lgkmcnt(0)" ::);                                    \
    __builtin_amdgcn_sched_barrier(0);                                          \
    __builtin_amdgcn_s_setprio(1);                                              \
    MFMA_SET(4, bfr)                                                            \
    __builtin_amdgcn_s_setprio(0);                                              \
    __syncthreads();  /* one drain+barrier per K-tile: t+1 ready, slot reusable */ \
  }

  STAGE_ALL(0, 0);
  __syncthreads();

  for (int t = 0; t < 15; ++t)
    KITER(t, 1)
  KITER(15, 0)

#undef KITER
#undef MFMA_SET
#undef STAGE_ALL
#undef AQOFF
#undef BOFF

  // ================= epilogue (spill-proof, LDS-staged) =================
  u16*   Csh = (u16*)lds_raw;                 // [256][264] padded pitch
  float* red = (float*)(lds_raw + 135168);    // [256][4][2]

  float bsv[4];
#pragma unroll
  for (int j = 0; j < 4; ++j) bsv[j] = bias[nt * 256 + wc * 64 + j * 16 + ln];

#pragma unroll
  for (int i = 0; i < 8; ++i) {
    float s1[4] = {0.f, 0.f, 0.f, 0.f}, s2[4] = {0.f, 0.f, 0.f, 0.f};
#pragma unroll
    for (int j = 0; j < 4; ++j) {
#pragma unroll
      for (int r = 0; r < 4; ++r) {
        float c = celu_f(acc[i][j][r] + bsv[j]);
        s1[r] += c; s2[r] += c * c;
        int rl = wr * 128 + i * 16 + 4 * lg + r;
        Csh[rl * 264 + wc * 64 + j * 16 + ln] = f2bf(c);
      }
    }
#pragma unroll
    for (int r = 0; r < 4; ++r) {
#pragma unroll
      for (int m = 1; m < 16; m <<= 1) {
        s1[r] += __shfl_xor(s1[r], m); s2[r] += __shfl_xor(s2[r], m);
      }
      if (ln == 0) {
        int rl = wr * 128 + i * 16 + 4 * lg + r;
        red[(rl * 4 + wc) * 2 + 0] = s1[r];
        red[(rl * 4 + wc) * 2 + 1] = s2[r];
      }
    }
  }
  __syncthreads();

  const int rsub = tid >> 5;
  const int cseg = (tid & 31) * 8;
  const int g2   = (cseg >> 7) * 2;
#pragma unroll 4
  for (int s = 0; s < 16; ++s) {
    int row_l = s * 16 + rsub;
    float s1t = red[(row_l * 4 + g2) * 2 + 0] + red[(row_l * 4 + g2 + 1) * 2 + 0];
    float s2t = red[(row_l * 4 + g2) * 2 + 1] + red[(row_l * 4 + g2 + 1) * 2 + 1];
    float mean = s1t * 0.0078125f;
    float var  = s2t * 0.0078125f - mean * mean;
    float inv  = rsqrtf(var + 1e-5f);
    u16x8 cv = *(const u16x8*)(Csh + row_l * 264 + cseg);
    int col0 = nt * 256 + cseg;
    f32x4 g0 = *(const f32x4*)(gamma + col0);
    f32x4 g1 = *(const f32x4*)(gamma + col0 + 4);
    f32x4 b0 = *(const f32x4*)(beta + col0);
    f32x4 b1 = *(const f32x4*)(beta + col0 + 4);
    u16x8 ov;
#pragma unroll
    for (int e = 0; e < 4; ++e) {
      ov[e]     = f2bf((bf2f(cv[e])     - mean) * inv * g0[e] + b0[e]);
      ov[4 + e] = f2bf((bf2f(cv[4 + e]) - mean) * inv * g1[e] + b1[e]);
    }
    *(u16x8*)(Cout + (long)(mt * 256 + row_l) * 1024 + col0) = ov;
  }
}

// ---------------------------------------------------------------------------
// Stage 2: am MFMA + pools + softmax + vectorized PV (round-8 verified).
// ---------------------------------------------------------------------------
__global__ __launch_bounds__(256) void stage2(
    const float* __restrict__ qb, const float* __restrict__ v1b,
    const u16* __restrict__ kbuf, const u16* __restrict__ v2buf,
    const u16* __restrict__ wbT, const float* __restrict__ bb,
    const float* __restrict__ Wl, const float* __restrict__ bl,
    const float* __restrict__ Wl2, const float* __restrict__ bl2,
    const float* __restrict__ mask, float* __restrict__ out)
{
  const int bh = blockIdx.x, b = bh >> 3, h = bh & 7;
  const int tid = threadIdx.x, lane = tid & 63, w = tid >> 6;
  const int lg = lane >> 4, ln = lane & 15;

  __shared__ float s_arr[1024];
  __shared__ float pool_l[4][64];
  __shared__ float poolf[64];
  __shared__ float ach[128];
  __shared__ float psum2[4][128];
  __shared__ float rmsk[4], rmax[4], rsum[4];

  float qv[4][8];
#pragma unroll
  for (int ks = 0; ks < 4; ++ks)
#pragma unroll
    for (int e = 0; e < 8; ++e)
      qv[ks][e] = qb[b * 1024 + h * 128 + ks * 32 + lg * 8 + e];

  s16x8 bfr[4][4];
#pragma unroll
  for (int nj = 0; nj < 4; ++nj)
#pragma unroll
    for (int ks = 0; ks < 4; ++ks)
      bfr[nj][ks] = *(const s16x8*)(&wbT[(nj * 16 + ln) * 128 + ks * 32 + lg * 8]);

  float wlv[4], bbv[4];
#pragma unroll
  for (int nj = 0; nj < 4; ++nj) { wlv[nj] = Wl[nj * 16 + ln]; bbv[nj] = bb[nj * 16 + ln]; }

  float mpart = 0.f;
  for (int m = tid; m < 1024; m += 256) mpart += mask[b * 1024 + m];

  float poolacc[4] = {0.f, 0.f, 0.f, 0.f};

  for (int c = 0; c < 16; ++c) {
    const int m0 = w * 256 + c * 16;
    f32x4 amacc[4] = {};
#pragma unroll
    for (int ks = 0; ks < 4; ++ks) {
      const u16* kp = kbuf + (long)(b * 1024 + m0 + ln) * 1024 + h * 128 + ks * 32 + lg * 8;
      u16x8 kw = *(const u16x8*)kp;
      s16x8 af;
#pragma unroll
      for (int e = 0; e < 8; ++e) af[e] = (short)f2bf(bf2f(kw[e]) * qv[ks][e]);
#pragma unroll
      for (int nj = 0; nj < 4; ++nj)
        amacc[nj] = __builtin_amdgcn_mfma_f32_16x16x32_bf16(af, bfr[nj][ks], amacc[nj], 0, 0, 0);
    }
    float mrow[4];
#pragma unroll
    for (int r = 0; r < 4; ++r) mrow[r] = mask[b * 1024 + m0 + lg * 4 + r];
    float sp[4] = {0.f, 0.f, 0.f, 0.f};
#pragma unroll
    for (int nj = 0; nj < 4; ++nj)
#pragma unroll
      for (int r = 0; r < 4; ++r) {
        float a = fmaxf(amacc[nj][r] + bbv[nj], 0.f);
        poolacc[nj] += a * mrow[r];
        sp[r] += a * wlv[nj];
      }
#pragma unroll
    for (int m = 1; m < 16; m <<= 1)
#pragma unroll
      for (int r = 0; r < 4; ++r) sp[r] += __shfl_xor(sp[r], m);
    if (ln == 0) {
#pragma unroll
      for (int r = 0; r < 4; ++r) s_arr[m0 + lg * 4 + r] = sp[r] + bl[0];
    }
  }
#pragma unroll
  for (int m = 16; m < 64; m <<= 1)
#pragma unroll
    for (int nj = 0; nj < 4; ++nj) poolacc[nj] += __shfl_xor(poolacc[nj], m);
  if (lg == 0) {
#pragma unroll
    for (int nj = 0; nj < 4; ++nj) pool_l[w][nj * 16 + ln] = poolacc[nj];
  }
#pragma unroll
  for (int m = 1; m < 64; m <<= 1) mpart += __shfl_xor(mpart, m);
  if (lane == 0) rmsk[w] = mpart;
  __syncthreads();   // B1
  const float msum = rmsk[0] + rmsk[1] + rmsk[2] + rmsk[3];
  if (tid < 64) poolf[tid] = pool_l[0][tid] + pool_l[1][tid] + pool_l[2][tid] + pool_l[3][tid];
  float lmax = -3.0e38f;
  for (int m = tid; m < 1024; m += 256) {
    float sv = (mask[b * 1024 + m] == 0.f) ? -1.0e9f : s_arr[m];
    s_arr[m] = sv;
    lmax = fmaxf(lmax, sv);
  }
#pragma unroll
  for (int m = 1; m < 64; m <<= 1) lmax = fmaxf(lmax, __shfl_xor(lmax, m));
  if (lane == 0) rmax[w] = lmax;
  __syncthreads();   // B2
  const float gmax = fmaxf(fmaxf(rmax[0], rmax[1]), fmaxf(rmax[2], rmax[3]));
  float lsum = 0.f;
  for (int m = tid; m < 1024; m += 256) {
    float e = expf(s_arr[m] - gmax);
    s_arr[m] = e;
    lsum += e;
  }
#pragma unroll
  for (int m = 1; m < 64; m <<= 1) lsum += __shfl_xor(lsum, m);
  if (lane == 0) rsum[w] = lsum;
  if (tid < 128) {
    float a = 0.f;
    for (int cc = 0; cc < 64; ++cc) a += poolf[cc] * Wl2[cc * 128 + tid];
    a = a / msum + bl2[tid];
    ach[tid] = 1.f / (1.f + expf(-a));
  }
  __syncthreads();   // B3
  const float gsum = rsum[0] + rsum[1] + rsum[2] + rsum[3];

  float pacc[8] = {0.f, 0.f, 0.f, 0.f, 0.f, 0.f, 0.f, 0.f};
  const u16* vbase = v2buf + (long)(b * 1024 + w * 256) * 1024 + h * 128 + ln * 8;
#pragma unroll 4
  for (int i = 0; i < 64; ++i) {
    const int mrow = i * 4 + lg;
    u16x8 vv = *(const u16x8*)(vbase + (long)mrow * 1024);
    float s = s_arr[w * 256 + mrow];
#pragma unroll
    for (int e = 0; e < 8; ++e) pacc[e] += s * bf2f(vv[e]);
  }
#pragma unroll
  for (int e = 0; e < 8; ++e) {
    pacc[e] += __shfl_xor(pacc[e], 16);
    pacc[e] += __shfl_xor(pacc[e], 32);
  }
  if (lg == 0) {
    f32x4 p0 = {pacc[0], pacc[1], pacc[2], pacc[3]};
    f32x4 p1 = {pacc[4], pacc[5], pacc[6], pacc[7]};
    *(f32x4*)&psum2[w][ln * 8]     = p0;
    *(f32x4*)&psum2[w][ln * 8 + 4] = p1;
  }
  __syncthreads();   // B4
  if (tid < 128) {
    float pooled = (psum2[0][tid] + psum2[1][tid] + psum2[2][tid] + psum2[3][tid]) / gsum;
    out[b * 1024 + h * 128 + tid] = v1b[b * 1024 + h * 128 + tid] * pooled * ach[tid];
  }
}

// ---------------------------------------------------------------------------
extern "C" void kernel_launch(void* const* d_in, const int* in_sizes, int n_in,
                              void* d_out, int out_size, void* d_ws, size_t ws_size,
                              hipStream_t stream)
{
  (void)in_sizes; (void)n_in; (void)out_size; (void)ws_size;
  const float* query  = (const float*)d_in[0];
  const float* key    = (const float*)d_in[1];
  const float* mask   = (const float*)d_in[2];
  const float* value1 = (const float*)d_in[3];
  const float* value2 = (const float*)d_in[4];
  const float* Wq  = (const float*)d_in[5];
  const float* bq  = (const float*)d_in[6];
  const float* gq  = (const float*)d_in[7];
  const float* gbq = (const float*)d_in[8];
  const float* Wk  = (const float*)d_in[9];
  const float* bk  = (const float*)d_in[10];
  const float* gk  = (const float*)d_in[11];
  const float* gbk = (const float*)d_in[12];
  const float* Wv1  = (const float*)d_in[13];
  const float* bv1  = (const float*)d_in[14];
  const float* gv1  = (const float*)d_in[15];
  const float* gbv1 = (const float*)d_in[16];
  const float* Wv2  = (const float*)d_in[17];
  const float* bv2  = (const float*)d_in[18];
  const float* gv2  = (const float*)d_in[19];
  const float* gbv2 = (const float*)d_in[20];
  const float* Wb  = (const float*)d_in[21];
  const float* bb  = (const float*)d_in[22];
  const float* Wl  = (const float*)d_in[23];
  const float* bl  = (const float*)d_in[24];
  const float* Wl2 = (const float*)d_in[25];
  const float* bl2 = (const float*)d_in[26];
  float* out = (float*)d_out;

  char* ws = (char*)d_ws;
  const long SZ128 = 134217728L;
  u16*   convA  = (u16*)(ws);                 // reused for key then value2
  u16*   k_out  = (u16*)(ws + SZ128);
  u16*   v2_out = (u16*)(ws + 2 * SZ128);
  char*  wbase  = ws + 3 * SZ128;
  u16*   WkT    = (u16*)(wbase);
  u16*   Wv2T   = (u16*)(wbase + 2097152L);
  u16*   WbT    = (u16*)(wbase + 2L * 2097152L);
  float* qbuf   = (float*)(wbase + 2L * 2097152L + 32768L);
  float* v1buf  = (float*)(wbase + 2L * 2097152L + 32768L + 262144L);

  dim3 tb(32, 8);
  transpose2_bf16<<<dim3(32, 64), tb, 0, stream>>>(Wk, WkT, Wv2, Wv2T);
  transpose_bf16<<<dim3(2, 4), tb, 0, stream>>>(Wb, WbT, 128, 64);

  branch_small2<<<1024, 128, 0, stream>>>(query, Wq, bq, gq, gbq, qbuf,
                                          value1, Wv1, bv1, gv1, gbv1, v1buf);

  convert_bf16<<<4096, 256, 0, stream>>>(key, convA, 67108864L);
  gemm256p2<<<1024, 512, 0, stream>>>(convA, WkT, bk, gk, gbk, k_out);

  convert_bf16<<<4096, 256, 0, stream>>>(value2, convA, 67108864L);
  gemm256p2<<<1024, 512, 0, stream>>>(convA, Wv2T, bv2, gv2, gbv2, v2_out);

  stage2<<<512, 256, 0, stream>>>(qbuf, v1buf, k_out, v2_out, WbT,
                                  bb, Wl, bl, Wl2, bl2, mask, out);
}

// Round 14
// 621.606 us; speedup vs baseline: 1.1105x; 1.1105x over previous
//
#include <hip/hip_runtime.h>

typedef unsigned short u16;
typedef __attribute__((ext_vector_type(8))) short s16x8;
typedef __attribute__((ext_vector_type(8))) unsigned short u16x8;
typedef __attribute__((ext_vector_type(4))) float f32x4;

#define AS1 __attribute__((address_space(1)))
#define AS3 __attribute__((address_space(3)))

__device__ __forceinline__ float bf2f(u16 u) {
  union { unsigned u; float f; } x; x.u = ((unsigned)u) << 16; return x.f;
}
__device__ __forceinline__ u16 f2bf(float f) {
  union { float f; unsigned u; } x; x.f = f;
  unsigned r = x.u + 0x7fffu + ((x.u >> 16) & 1u);
  return (u16)(r >> 16);
}
// fast CELU: native v_exp instead of libm expm1f (rel err ~2e-7, safe vs
// 3x absmax headroom; saves ~13 VALU ops per element in the hot epilogue)
__device__ __forceinline__ float celu_f(float x) {
  return x > 0.f ? x : 1.3f * (__expf(x * (1.0f / 1.3f)) - 1.0f);
}

// ---------------------------------------------------------------------------
// fp32 -> bf16 elementwise convert (HBM-bound). n multiple of 8.
// ---------------------------------------------------------------------------
__global__ __launch_bounds__(256) void convert_bf16(
    const float* __restrict__ X, u16* __restrict__ Y, long n)
{
  long i = ((long)blockIdx.x * 256 + threadIdx.x) * 8;
  const long stride = (long)gridDim.x * 256 * 8;
  for (; i < n; i += stride) {
    f32x4 a = *(const f32x4*)(X + i);
    f32x4 b = *(const f32x4*)(X + i + 4);
    u16x8 t;
#pragma unroll
    for (int e = 0; e < 4; ++e) { t[e] = f2bf(a[e]); t[4 + e] = f2bf(b[e]); }
    *(u16x8*)(Y + i) = t;
  }
}

// ---------------------------------------------------------------------------
// Transpose + fp32->bf16 for Wk, Wv2 (1024x1024) AND Wb (128x64) in ONE
// dispatch.  grid(32, 65): y<32 -> Wk, y<64 -> Wv2, y==64 -> Wb (bx<8).
// ---------------------------------------------------------------------------
__global__ __launch_bounds__(256) void transpose3_bf16(
    const float* __restrict__ W0, u16* __restrict__ WT0,
    const float* __restrict__ W1, u16* __restrict__ WT1,
    const float* __restrict__ Wb, u16* __restrict__ WbT)
{
  __shared__ float tile[32][33];
  const int bx = blockIdx.x;
  const int tx = threadIdx.x, ty = threadIdx.y;
  if (blockIdx.y < 64) {
    const int sel = blockIdx.y >> 5;
    const int by = blockIdx.y & 31;
    const float* W = sel ? W1 : W0;
    u16* WT = sel ? WT1 : WT0;
#pragma unroll
    for (int i = ty; i < 32; i += 8)
      tile[i][tx] = W[(by * 32 + i) * 1024 + bx * 32 + tx];
    __syncthreads();
#pragma unroll
    for (int i = ty; i < 32; i += 8)
      WT[(bx * 32 + i) * 1024 + by * 32 + tx] = f2bf(tile[tx][i]);
  } else {
    if (bx >= 8) return;
    const int cx2 = bx & 1;        // col tile within C=64
    const int by2 = bx >> 1;       // row tile within R=128
#pragma unroll
    for (int i = ty; i < 32; i += 8)
      tile[i][tx] = Wb[(by2 * 32 + i) * 64 + cx2 * 32 + tx];
    __syncthreads();
#pragma unroll
    for (int i = ty; i < 32; i += 8)
      WbT[(cx2 * 32 + i) * 128 + by2 * 32 + tx] = f2bf(tile[tx][i]);
  }
}

// ---------------------------------------------------------------------------
// q AND v1 branch in one dispatch (fp32): out = groupnorm(celu(X@W + b)).
// grid 1024: bid<512 -> (query path), else (value1 path).
// ---------------------------------------------------------------------------
__global__ __launch_bounds__(128) void branch_small2(
    const float* __restrict__ X0, const float* __restrict__ W0,
    const float* __restrict__ b0, const float* __restrict__ g0,
    const float* __restrict__ be0, float* __restrict__ o0,
    const float* __restrict__ X1, const float* __restrict__ W1,
    const float* __restrict__ b1, const float* __restrict__ g1,
    const float* __restrict__ be1, float* __restrict__ o1)
{
  const int bid = blockIdx.x;
  const int sel = bid >> 9;
  const float* X = sel ? X1 : X0;  const float* W = sel ? W1 : W0;
  const float* bias = sel ? b1 : b0; const float* gamma = sel ? g1 : g0;
  const float* beta = sel ? be1 : be0; float* out = sel ? o1 : o0;
  const int b = (bid & 511) >> 3, grp = bid & 7;
  const int t = threadIdx.x;
  __shared__ float xs[1024];
  __shared__ float r1[2], r2[2];
  for (int i = t; i < 1024; i += 128) xs[i] = X[b * 1024 + i];
  __syncthreads();
  const int col = grp * 128 + t;
  const float* wp = W + col;
  float a0 = 0.f, a1 = 0.f, a2 = 0.f, a3 = 0.f;
  for (int k = 0; k < 1024; k += 4) {
    a0 += xs[k]     * wp[(k)     * 1024];
    a1 += xs[k + 1] * wp[(k + 1) * 1024];
    a2 += xs[k + 2] * wp[(k + 2) * 1024];
    a3 += xs[k + 3] * wp[(k + 3) * 1024];
  }
  float x = (a0 + a1) + (a2 + a3) + bias[col];
  float c = celu_f(x);
  float s1 = c, s2 = c * c;
#pragma unroll
  for (int m = 1; m < 64; m <<= 1) { s1 += __shfl_xor(s1, m); s2 += __shfl_xor(s2, m); }
  const int w = t >> 6;
  if ((t & 63) == 0) { r1[w] = s1; r2[w] = s2; }
  __syncthreads();
  float t1 = r1[0] + r1[1], t2 = r2[0] + r2[1];
  float mean = t1 * 0.0078125f;
  float var  = t2 * 0.0078125f - mean * mean;
  float inv  = rsqrtf(var + 1e-5f);
  out[b * 1024 + col] = (c - mean) * inv * gamma[col] + beta[col];
}

// ---------------------------------------------------------------------------
// 256x256-tile, BK=64, 8-wave GEMM — T3 minimum 2-phase sync (round-13
// verified, frozen): C = groupnorm(celu(A @ W + b)) in bf16.
// ---------------------------------------------------------------------------
__global__ void
__attribute__((amdgpu_flat_work_group_size(512, 512), amdgpu_waves_per_eu(2, 2)))
gemm256p2(
    const u16* __restrict__ A16, const u16* __restrict__ WT,
    const float* __restrict__ bias, const float* __restrict__ gamma,
    const float* __restrict__ beta, u16* __restrict__ Cout)
{
  __shared__ __align__(16) char lds_raw[143360];

  const int tid  = threadIdx.x;
  const int lane = tid & 63;
  const int w    = tid >> 6;
  const int wr   = w >> 2, wc = w & 3;
  const int lg   = lane >> 4, ln = lane & 15;

  const int bid = blockIdx.x;
  const int v   = (bid & 7) * 128 + (bid >> 3);
  const int mt  = v >> 2, nt = v & 3;

  const int trow = tid >> 3;
  const int gsw  = ((tid & 7) ^ (trow & 7)) * 8;
  const u16* aS00 = A16 + (long)(mt * 256 +   0 +  0 + trow) * 1024 + gsw;
  const u16* aS01 = A16 + (long)(mt * 256 +   0 + 64 + trow) * 1024 + gsw;
  const u16* aS10 = A16 + (long)(mt * 256 + 128 +  0 + trow) * 1024 + gsw;
  const u16* aS11 = A16 + (long)(mt * 256 + 128 + 64 + trow) * 1024 + gsw;
  const u16* bS0  = WT  + (long)(nt * 256 +   0 + trow) * 1024 + gsw;
  const u16* bS1  = WT  + (long)(nt * 256 +  64 + trow) * 1024 + gsw;
  const u16* bS2  = WT  + (long)(nt * 256 + 128 + trow) * 1024 + gsw;
  const u16* bS3  = WT  + (long)(nt * 256 + 192 + trow) * 1024 + gsw;

#define AQOFF(wr2, h, sl) ((((wr2) * 2 + (h)) * 2 + (sl)) * 8192)
#define BOFF(sl)          (65536 + (sl) * 32768)

#define STAGE_ALL(sl, kt)                                                       \
  { __builtin_amdgcn_global_load_lds((const AS1 void*)(bS0 + (kt) * 64),        \
        (AS3 void*)(lds_raw + BOFF(sl) +     0 + w * 1024), 16, 0, 0);          \
    __builtin_amdgcn_global_load_lds((const AS1 void*)(bS1 + (kt) * 64),        \
        (AS3 void*)(lds_raw + BOFF(sl) +  8192 + w * 1024), 16, 0, 0);          \
    __builtin_amdgcn_global_load_lds((const AS1 void*)(bS2 + (kt) * 64),        \
        (AS3 void*)(lds_raw + BOFF(sl) + 16384 + w * 1024), 16, 0, 0);          \
    __builtin_amdgcn_global_load_lds((const AS1 void*)(bS3 + (kt) * 64),        \
        (AS3 void*)(lds_raw + BOFF(sl) + 24576 + w * 1024), 16, 0, 0);          \
    __builtin_amdgcn_global_load_lds((const AS1 void*)(aS00 + (kt) * 64),       \
        (AS3 void*)(lds_raw + AQOFF(0, 0, sl) + w * 1024), 16, 0, 0);           \
    __builtin_amdgcn_global_load_lds((const AS1 void*)(aS10 + (kt) * 64),       \
        (AS3 void*)(lds_raw + AQOFF(1, 0, sl) + w * 1024), 16, 0, 0);           \
    __builtin_amdgcn_global_load_lds((const AS1 void*)(aS01 + (kt) * 64),       \
        (AS3 void*)(lds_raw + AQOFF(0, 1, sl) + w * 1024), 16, 0, 0);           \
    __builtin_amdgcn_global_load_lds((const AS1 void*)(aS11 + (kt) * 64),       \
        (AS3 void*)(lds_raw + AQOFF(1, 1, sl) + w * 1024), 16, 0, 0); }

  int aoff0[4], aoff1[4], boff0[4], boff1[4];
#pragma unroll
  for (int la = 0; la < 4; ++la) {
    int rq = la * 16 + ln;
    aoff0[la] = rq * 128 + (((0 * 4 + lg) ^ (ln & 7)) * 16);
    aoff1[la] = rq * 128 + (((1 * 4 + lg) ^ (ln & 7)) * 16);
  }
#pragma unroll
  for (int j = 0; j < 4; ++j) {
    int nl = wc * 64 + j * 16 + ln;
    boff0[j] = nl * 128 + (((0 * 4 + lg) ^ (ln & 7)) * 16);
    boff1[j] = nl * 128 + (((1 * 4 + lg) ^ (ln & 7)) * 16);
  }

  f32x4 acc[8][4] = {};

#define MFMA_SET(IB, BF)                                                        \
    _Pragma("unroll")                                                           \
    for (int la = 0; la < 4; ++la)                                              \
      _Pragma("unroll")                                                         \
      for (int j = 0; j < 4; ++j)                                               \
        acc[(IB) + la][j] = __builtin_amdgcn_mfma_f32_16x16x32_bf16(            \
            afv[la], BF[j], acc[(IB) + la][j], 0, 0, 0);

#define KITER(T, STG)                                                           \
  {                                                                             \
    const int slot = (T) & 1, nslot = slot ^ 1;                                 \
    const char* aqb0 = lds_raw + AQOFF(wr, 0, slot);                            \
    const char* aqb1 = lds_raw + AQOFF(wr, 1, slot);                            \
    const char* bqb  = lds_raw + BOFF(slot);                                    \
    s16x8 bfr[4], afv[4];                                                       \
    if (STG) STAGE_ALL(nslot, (T) + 1);                                         \
    /* cluster 1: low x ks0 */                                                  \
    _Pragma("unroll")                                                           \
    for (int la = 0; la < 4; ++la) afv[la] = *(const s16x8*)(aqb0 + aoff0[la]); \
    _Pragma("unroll")                                                           \
    for (int j = 0; j < 4; ++j) bfr[j] = *(const s16x8*)(bqb + boff0[j]);       \
    asm volatile("s_waitcnt lgkmcnt(0)" ::);                                    \
    __builtin_amdgcn_sched_barrier(0);                                          \
    __builtin_amdgcn_s_setprio(1);                                              \
    MFMA_SET(0, bfr)                                                            \
    __builtin_amdgcn_s_setprio(0);                                              \
    /* cluster 2: up x ks0 */                                                   \
    _Pragma("unroll")                                                           \
    for (int la = 0; la < 4; ++la) afv[la] = *(const s16x8*)(aqb1 + aoff0[la]); \
    asm volatile("s_waitcnt lgkmcnt(0)" ::);                                    \
    __builtin_amdgcn_sched_barrier(0);                                          \
    __builtin_amdgcn_s_setprio(1);                                              \
    MFMA_SET(4, bfr)                                                            \
    __builtin_amdgcn_s_setprio(0);                                              \
    /* cluster 3: low x ks1 */                                                  \
    _Pragma("unroll")                                                           \
    for (int la = 0; la < 4; ++la) afv[la] = *(const s16x8*)(aqb0 + aoff1[la]); \
    _Pragma("unroll")                                                           \
    for (int j = 0; j < 4; ++j) bfr[j] = *(const s16x8*)(bqb + boff1[j]);       \
    asm volatile("s_waitcnt lgkmcnt(0)" ::);                                    \
    __builtin_amdgcn_sched_barrier(0);                                          \
    __builtin_amdgcn_s_setprio(1);                                              \
    MFMA_SET(0, bfr)                                                            \
    __builtin_amdgcn_s_setprio(0);                                              \
    /* cluster 4: up x ks1 */                                                   \
    _Pragma("unroll")                                                           \
    for (int la = 0; la < 4; ++la) afv[la] = *(const s16x8*)(aqb1 + aoff1[la]); \
    asm volatile("s_waitcnt lgkmcnt(0)" ::);                                    \
    __builtin_amdgcn_sched_barrier(0);                                          \
    __builtin_amdgcn_s_setprio(1);                                              \
    MFMA_SET(4, bfr)                                                            \
    __builtin_amdgcn_s_setprio(0);                                              \
    __syncthreads();  /* one drain+barrier per K-tile */                        \
  }

  STAGE_ALL(0, 0);
  __syncthreads();

  for (int t = 0; t < 15; ++t)
    KITER(t, 1)
  KITER(15, 0)

#undef KITER
#undef MFMA_SET
#undef STAGE_ALL
#undef AQOFF
#undef BOFF

  // ================= epilogue (spill-proof, LDS-staged) =================
  u16*   Csh = (u16*)lds_raw;                 // [256][264] padded pitch
  float* red = (float*)(lds_raw + 135168);    // [256][4][2]

  float bsv[4];
#pragma unroll
  for (int j = 0; j < 4; ++j) bsv[j] = bias[nt * 256 + wc * 64 + j * 16 + ln];

#pragma unroll
  for (int i = 0; i < 8; ++i) {
    float s1[4] = {0.f, 0.f, 0.f, 0.f}, s2[4] = {0.f, 0.f, 0.f, 0.f};
#pragma unroll
    for (int j = 0; j < 4; ++j) {
#pragma unroll
      for (int r = 0; r < 4; ++r) {
        float c = celu_f(acc[i][j][r] + bsv[j]);
        s1[r] += c; s2[r] += c * c;
        int rl = wr * 128 + i * 16 + 4 * lg + r;
        Csh[rl * 264 + wc * 64 + j * 16 + ln] = f2bf(c);
      }
    }
#pragma unroll
    for (int r = 0; r < 4; ++r) {
#pragma unroll
      for (int m = 1; m < 16; m <<= 1) {
        s1[r] += __shfl_xor(s1[r], m); s2[r] += __shfl_xor(s2[r], m);
      }
      if (ln == 0) {
        int rl = wr * 128 + i * 16 + 4 * lg + r;
        red[(rl * 4 + wc) * 2 + 0] = s1[r];
        red[(rl * 4 + wc) * 2 + 1] = s2[r];
      }
    }
  }
  __syncthreads();

  const int rsub = tid >> 5;
  const int cseg = (tid & 31) * 8;
  const int g2   = (cseg >> 7) * 2;
#pragma unroll 4
  for (int s = 0; s < 16; ++s) {
    int row_l = s * 16 + rsub;
    float s1t = red[(row_l * 4 + g2) * 2 + 0] + red[(row_l * 4 + g2 + 1) * 2 + 0];
    float s2t = red[(row_l * 4 + g2) * 2 + 1] + red[(row_l * 4 + g2 + 1) * 2 + 1];
    float mean = s1t * 0.0078125f;
    float var  = s2t * 0.0078125f - mean * mean;
    float inv  = rsqrtf(var + 1e-5f);
    u16x8 cv = *(const u16x8*)(Csh + row_l * 264 + cseg);
    int col0 = nt * 256 + cseg;
    f32x4 g0 = *(const f32x4*)(gamma + col0);
    f32x4 g1 = *(const f32x4*)(gamma + col0 + 4);
    f32x4 b0 = *(const f32x4*)(beta + col0);
    f32x4 b1 = *(const f32x4*)(beta + col0 + 4);
    u16x8 ov;
#pragma unroll
    for (int e = 0; e < 4; ++e) {
      ov[e]     = f2bf((bf2f(cv[e])     - mean) * inv * g0[e] + b0[e]);
      ov[4 + e] = f2bf((bf2f(cv[4 + e]) - mean) * inv * g1[e] + b1[e]);
    }
    *(u16x8*)(Cout + (long)(mt * 256 + row_l) * 1024 + col0) = ov;
  }
}

// ---------------------------------------------------------------------------
// Stage 2: am MFMA + pools + softmax + vectorized PV (round-8 verified).
// ---------------------------------------------------------------------------
__global__ __launch_bounds__(256) void stage2(
    const float* __restrict__ qb, const float* __restrict__ v1b,
    const u16* __restrict__ kbuf, const u16* __restrict__ v2buf,
    const u16* __restrict__ wbT, const float* __restrict__ bb,
    const float* __restrict__ Wl, const float* __restrict__ bl,
    const float* __restrict__ Wl2, const float* __restrict__ bl2,
    const float* __restrict__ mask, float* __restrict__ out)
{
  const int bh = blockIdx.x, b = bh >> 3, h = bh & 7;
  const int tid = threadIdx.x, lane = tid & 63, w = tid >> 6;
  const int lg = lane >> 4, ln = lane & 15;

  __shared__ float s_arr[1024];
  __shared__ float pool_l[4][64];
  __shared__ float poolf[64];
  __shared__ float ach[128];
  __shared__ float psum2[4][128];
  __shared__ float rmsk[4], rmax[4], rsum[4];

  float qv[4][8];
#pragma unroll
  for (int ks = 0; ks < 4; ++ks)
#pragma unroll
    for (int e = 0; e < 8; ++e)
      qv[ks][e] = qb[b * 1024 + h * 128 + ks * 32 + lg * 8 + e];

  s16x8 bfr[4][4];
#pragma unroll
  for (int nj = 0; nj < 4; ++nj)
#pragma unroll
    for (int ks = 0; ks < 4; ++ks)
      bfr[nj][ks] = *(const s16x8*)(&wbT[(nj * 16 + ln) * 128 + ks * 32 + lg * 8]);

  float wlv[4], bbv[4];
#pragma unroll
  for (int nj = 0; nj < 4; ++nj) { wlv[nj] = Wl[nj * 16 + ln]; bbv[nj] = bb[nj * 16 + ln]; }

  float mpart = 0.f;
  for (int m = tid; m < 1024; m += 256) mpart += mask[b * 1024 + m];

  float poolacc[4] = {0.f, 0.f, 0.f, 0.f};

  for (int c = 0; c < 16; ++c) {
    const int m0 = w * 256 + c * 16;
    f32x4 amacc[4] = {};
#pragma unroll
    for (int ks = 0; ks < 4; ++ks) {
      const u16* kp = kbuf + (long)(b * 1024 + m0 + ln) * 1024 + h * 128 + ks * 32 + lg * 8;
      u16x8 kw = *(const u16x8*)kp;
      s16x8 af;
#pragma unroll
      for (int e = 0; e < 8; ++e) af[e] = (short)f2bf(bf2f(kw[e]) * qv[ks][e]);
#pragma unroll
      for (int nj = 0; nj < 4; ++nj)
        amacc[nj] = __builtin_amdgcn_mfma_f32_16x16x32_bf16(af, bfr[nj][ks], amacc[nj], 0, 0, 0);
    }
    float mrow[4];
#pragma unroll
    for (int r = 0; r < 4; ++r) mrow[r] = mask[b * 1024 + m0 + lg * 4 + r];
    float sp[4] = {0.f, 0.f, 0.f, 0.f};
#pragma unroll
    for (int nj = 0; nj < 4; ++nj)
#pragma unroll
      for (int r = 0; r < 4; ++r) {
        float a = fmaxf(amacc[nj][r] + bbv[nj], 0.f);
        poolacc[nj] += a * mrow[r];
        sp[r] += a * wlv[nj];
      }
#pragma unroll
    for (int m = 1; m < 16; m <<= 1)
#pragma unroll
      for (int r = 0; r < 4; ++r) sp[r] += __shfl_xor(sp[r], m);
    if (ln == 0) {
#pragma unroll
      for (int r = 0; r < 4; ++r) s_arr[m0 + lg * 4 + r] = sp[r] + bl[0];
    }
  }
#pragma unroll
  for (int m = 16; m < 64; m <<= 1)
#pragma unroll
    for (int nj = 0; nj < 4; ++nj) poolacc[nj] += __shfl_xor(poolacc[nj], m);
  if (lg == 0) {
#pragma unroll
    for (int nj = 0; nj < 4; ++nj) pool_l[w][nj * 16 + ln] = poolacc[nj];
  }
#pragma unroll
  for (int m = 1; m < 64; m <<= 1) mpart += __shfl_xor(mpart, m);
  if (lane == 0) rmsk[w] = mpart;
  __syncthreads();   // B1
  const float msum = rmsk[0] + rmsk[1] + rmsk[2] + rmsk[3];
  if (tid < 64) poolf[tid] = pool_l[0][tid] + pool_l[1][tid] + pool_l[2][tid] + pool_l[3][tid];
  float lmax = -3.0e38f;
  for (int m = tid; m < 1024; m += 256) {
    float sv = (mask[b * 1024 + m] == 0.f) ? -1.0e9f : s_arr[m];
    s_arr[m] = sv;
    lmax = fmaxf(lmax, sv);
  }
#pragma unroll
  for (int m = 1; m < 64; m <<= 1) lmax = fmaxf(lmax, __shfl_xor(lmax, m));
  if (lane == 0) rmax[w] = lmax;
  __syncthreads();   // B2
  const float gmax = fmaxf(fmaxf(rmax[0], rmax[1]), fmaxf(rmax[2], rmax[3]));
  float lsum = 0.f;
  for (int m = tid; m < 1024; m += 256) {
    float e = expf(s_arr[m] - gmax);
    s_arr[m] = e;
    lsum += e;
  }
#pragma unroll
  for (int m = 1; m < 64; m <<= 1) lsum += __shfl_xor(lsum, m);
  if (lane == 0) rsum[w] = lsum;
  if (tid < 128) {
    float a = 0.f;
    for (int cc = 0; cc < 64; ++cc) a += poolf[cc] * Wl2[cc * 128 + tid];
    a = a / msum + bl2[tid];
    ach[tid] = 1.f / (1.f + expf(-a));
  }
  __syncthreads();   // B3
  const float gsum = rsum[0] + rsum[1] + rsum[2] + rsum[3];

  float pacc[8] = {0.f, 0.f, 0.f, 0.f, 0.f, 0.f, 0.f, 0.f};
  const u16* vbase = v2buf + (long)(b * 1024 + w * 256) * 1024 + h * 128 + ln * 8;
#pragma unroll 4
  for (int i = 0; i < 64; ++i) {
    const int mrow = i * 4 + lg;
    u16x8 vv = *(const u16x8*)(vbase + (long)mrow * 1024);
    float s = s_arr[w * 256 + mrow];
#pragma unroll
    for (int e = 0; e < 8; ++e) pacc[e] += s * bf2f(vv[e]);
  }
#pragma unroll
  for (int e = 0; e < 8; ++e) {
    pacc[e] += __shfl_xor(pacc[e], 16);
    pacc[e] += __shfl_xor(pacc[e], 32);
  }
  if (lg == 0) {
    f32x4 p0 = {pacc[0], pacc[1], pacc[2], pacc[3]};
    f32x4 p1 = {pacc[4], pacc[5], pacc[6], pacc[7]};
    *(f32x4*)&psum2[w][ln * 8]     = p0;
    *(f32x4*)&psum2[w][ln * 8 + 4] = p1;
  }
  __syncthreads();   // B4
  if (tid < 128) {
    float pooled = (psum2[0][tid] + psum2[1][tid] + psum2[2][tid] + psum2[3][tid]) / gsum;
    out[b * 1024 + h * 128 + tid] = v1b[b * 1024 + h * 128 + tid] * pooled * ach[tid];
  }
}

// ---------------------------------------------------------------------------
extern "C" void kernel_launch(void* const* d_in, const int* in_sizes, int n_in,
                              void* d_out, int out_size, void* d_ws, size_t ws_size,
                              hipStream_t stream)
{
  (void)in_sizes; (void)n_in; (void)out_size; (void)ws_size;
  const float* query  = (const float*)d_in[0];
  const float* key    = (const float*)d_in[1];
  const float* mask   = (const float*)d_in[2];
  const float* value1 = (const float*)d_in[3];
  const float* value2 = (const float*)d_in[4];
  const float* Wq  = (const float*)d_in[5];
  const float* bq  = (const float*)d_in[6];
  const float* gq  = (const float*)d_in[7];
  const float* gbq = (const float*)d_in[8];
  const float* Wk  = (const float*)d_in[9];
  const float* bk  = (const float*)d_in[10];
  const float* gk  = (const float*)d_in[11];
  const float* gbk = (const float*)d_in[12];
  const float* Wv1  = (const float*)d_in[13];
  const float* bv1  = (const float*)d_in[14];
  const float* gv1  = (const float*)d_in[15];
  const float* gbv1 = (const float*)d_in[16];
  const float* Wv2  = (const float*)d_in[17];
  const float* bv2  = (const float*)d_in[18];
  const float* gv2  = (const float*)d_in[19];
  const float* gbv2 = (const float*)d_in[20];
  const float* Wb  = (const float*)d_in[21];
  const float* bb  = (const float*)d_in[22];
  const float* Wl  = (const float*)d_in[23];
  const float* bl  = (const float*)d_in[24];
  const float* Wl2 = (const float*)d_in[25];
  const float* bl2 = (const float*)d_in[26];
  float* out = (float*)d_out;

  char* ws = (char*)d_ws;
  const long SZ128 = 134217728L;
  u16*   convA  = (u16*)(ws);                 // reused for key then value2
  u16*   k_out  = (u16*)(ws + SZ128);
  u16*   v2_out = (u16*)(ws + 2 * SZ128);
  char*  wbase  = ws + 3 * SZ128;
  u16*   WkT    = (u16*)(wbase);
  u16*   Wv2T   = (u16*)(wbase + 2097152L);
  u16*   WbT    = (u16*)(wbase + 2L * 2097152L);
  float* qbuf   = (float*)(wbase + 2L * 2097152L + 32768L);
  float* v1buf  = (float*)(wbase + 2L * 2097152L + 32768L + 262144L);

  dim3 tb(32, 8);
  transpose3_bf16<<<dim3(32, 65), tb, 0, stream>>>(Wk, WkT, Wv2, Wv2T, Wb, WbT);

  branch_small2<<<1024, 128, 0, stream>>>(query, Wq, bq, gq, gbq, qbuf,
                                          value1, Wv1, bv1, gv1, gbv1, v1buf);

  convert_bf16<<<4096, 256, 0, stream>>>(key, convA, 67108864L);
  gemm256p2<<<1024, 512, 0, stream>>>(convA, WkT, bk, gk, gbk, k_out);

  convert_bf16<<<4096, 256, 0, stream>>>(value2, convA, 67108864L);
  gemm256p2<<<1024, 512, 0, stream>>>(convA, Wv2T, bv2, gv2, gbv2, v2_out);

  stage2<<<512, 256, 0, stream>>>(qbuf, v1buf, k_out, v2_out, WbT,
                                  bb, Wl, bl, Wl2, bl2, mask, out);
}

// Round 15
// 620.339 us; speedup vs baseline: 1.1128x; 1.0020x over previous
//
#include <hip/hip_runtime.h>

typedef unsigned short u16;
typedef __attribute__((ext_vector_type(8))) short s16x8;
typedef __attribute__((ext_vector_type(8))) unsigned short u16x8;
typedef __attribute__((ext_vector_type(4))) float f32x4;

#define AS1 __attribute__((address_space(1)))
#define AS3 __attribute__((address_space(3)))

__device__ __forceinline__ float bf2f(u16 u) {
  union { unsigned u; float f; } x; x.u = ((unsigned)u) << 16; return x.f;
}
__device__ __forceinline__ u16 f2bf(float f) {
  union { float f; unsigned u; } x; x.f = f;
  unsigned r = x.u + 0x7fffu + ((x.u >> 16) & 1u);
  return (u16)(r >> 16);
}
// fast CELU: native v_exp (round-14 verified: −37us/gemm vs libm expm1f)
__device__ __forceinline__ float celu_f(float x) {
  return x > 0.f ? x : 1.3f * (__expf(x * (1.0f / 1.3f)) - 1.0f);
}

// ---------------------------------------------------------------------------
// fp32 -> bf16 elementwise convert (HBM-bound). n multiple of 8.
// ---------------------------------------------------------------------------
__global__ __launch_bounds__(256) void convert_bf16(
    const float* __restrict__ X, u16* __restrict__ Y, long n)
{
  long i = ((long)blockIdx.x * 256 + threadIdx.x) * 8;
  const long stride = (long)gridDim.x * 256 * 8;
  for (; i < n; i += stride) {
    f32x4 a = *(const f32x4*)(X + i);
    f32x4 b = *(const f32x4*)(X + i + 4);
    u16x8 t;
#pragma unroll
    for (int e = 0; e < 4; ++e) { t[e] = f2bf(a[e]); t[4 + e] = f2bf(b[e]); }
    *(u16x8*)(Y + i) = t;
  }
}

// ---------------------------------------------------------------------------
// Transpose + fp32->bf16 for Wk, Wv2 (1024x1024) AND Wb (128x64) in ONE
// dispatch.  grid(32, 65): y<32 -> Wk, y<64 -> Wv2, y==64 -> Wb (bx<8).
// ---------------------------------------------------------------------------
__global__ __launch_bounds__(256) void transpose3_bf16(
    const float* __restrict__ W0, u16* __restrict__ WT0,
    const float* __restrict__ W1, u16* __restrict__ WT1,
    const float* __restrict__ Wb, u16* __restrict__ WbT)
{
  __shared__ float tile[32][33];
  const int bx = blockIdx.x;
  const int tx = threadIdx.x, ty = threadIdx.y;
  if (blockIdx.y < 64) {
    const int sel = blockIdx.y >> 5;
    const int by = blockIdx.y & 31;
    const float* W = sel ? W1 : W0;
    u16* WT = sel ? WT1 : WT0;
#pragma unroll
    for (int i = ty; i < 32; i += 8)
      tile[i][tx] = W[(by * 32 + i) * 1024 + bx * 32 + tx];
    __syncthreads();
#pragma unroll
    for (int i = ty; i < 32; i += 8)
      WT[(bx * 32 + i) * 1024 + by * 32 + tx] = f2bf(tile[tx][i]);
  } else {
    if (bx >= 8) return;
    const int cx2 = bx & 1;
    const int by2 = bx >> 1;
#pragma unroll
    for (int i = ty; i < 32; i += 8)
      tile[i][tx] = Wb[(by2 * 32 + i) * 64 + cx2 * 32 + tx];
    __syncthreads();
#pragma unroll
    for (int i = ty; i < 32; i += 8)
      WbT[(cx2 * 32 + i) * 128 + by2 * 32 + tx] = f2bf(tile[tx][i]);
  }
}

// ---------------------------------------------------------------------------
// q AND v1 branch in one dispatch (fp32): out = groupnorm(celu(X@W + b)).
// ---------------------------------------------------------------------------
__global__ __launch_bounds__(128) void branch_small2(
    const float* __restrict__ X0, const float* __restrict__ W0,
    const float* __restrict__ b0, const float* __restrict__ g0,
    const float* __restrict__ be0, float* __restrict__ o0,
    const float* __restrict__ X1, const float* __restrict__ W1,
    const float* __restrict__ b1, const float* __restrict__ g1,
    const float* __restrict__ be1, float* __restrict__ o1)
{
  const int bid = blockIdx.x;
  const int sel = bid >> 9;
  const float* X = sel ? X1 : X0;  const float* W = sel ? W1 : W0;
  const float* bias = sel ? b1 : b0; const float* gamma = sel ? g1 : g0;
  const float* beta = sel ? be1 : be0; float* out = sel ? o1 : o0;
  const int b = (bid & 511) >> 3, grp = bid & 7;
  const int t = threadIdx.x;
  __shared__ float xs[1024];
  __shared__ float r1[2], r2[2];
  for (int i = t; i < 1024; i += 128) xs[i] = X[b * 1024 + i];
  __syncthreads();
  const int col = grp * 128 + t;
  const float* wp = W + col;
  float a0 = 0.f, a1 = 0.f, a2 = 0.f, a3 = 0.f;
  for (int k = 0; k < 1024; k += 4) {
    a0 += xs[k]     * wp[(k)     * 1024];
    a1 += xs[k + 1] * wp[(k + 1) * 1024];
    a2 += xs[k + 2] * wp[(k + 2) * 1024];
    a3 += xs[k + 3] * wp[(k + 3) * 1024];
  }
  float x = (a0 + a1) + (a2 + a3) + bias[col];
  float c = celu_f(x);
  float s1 = c, s2 = c * c;
#pragma unroll
  for (int m = 1; m < 64; m <<= 1) { s1 += __shfl_xor(s1, m); s2 += __shfl_xor(s2, m); }
  const int w = t >> 6;
  if ((t & 63) == 0) { r1[w] = s1; r2[w] = s2; }
  __syncthreads();
  float t1 = r1[0] + r1[1], t2 = r2[0] + r2[1];
  float mean = t1 * 0.0078125f;
  float var  = t2 * 0.0078125f - mean * mean;
  float inv  = rsqrtf(var + 1e-5f);
  out[b * 1024 + col] = (c - mean) * inv * gamma[col] + beta[col];
}

// ---------------------------------------------------------------------------
// 256x256-tile, BK=64, 8-wave GEMM, T3-minimum 2-phase sync, UNPINNED body:
// per K-tile: STAGE(nslot, t+1) first, then 4 read-clusters + MFMA sets with
// COMPILER-managed waitcnts (C++ ds_reads -> dep-tracking emits fine-grained
// lgkmcnt; manual lgkmcnt(0)+sched_barrier pins removed — they over-
// constrained the scheduler, m141 lesson), then ONE __syncthreads per tile.
// Fast-celu LDS-staged GroupNorm epilogue (round-14 verified).
// grid 1024 (bijective XCD swizzle), block 512, 1 block/CU.
// ---------------------------------------------------------------------------
__global__ void
__attribute__((amdgpu_flat_work_group_size(512, 512), amdgpu_waves_per_eu(2, 2)))
gemm256p3(
    const u16* __restrict__ A16, const u16* __restrict__ WT,
    const float* __restrict__ bias, const float* __restrict__ gamma,
    const float* __restrict__ beta, u16* __restrict__ Cout)
{
  __shared__ __align__(16) char lds_raw[143360];

  const int tid  = threadIdx.x;
  const int lane = tid & 63;
  const int w    = tid >> 6;
  const int wr   = w >> 2, wc = w & 3;
  const int lg   = lane >> 4, ln = lane & 15;

  const int bid = blockIdx.x;
  const int v   = (bid & 7) * 128 + (bid >> 3);
  const int mt  = v >> 2, nt = v & 3;

  const int trow = tid >> 3;
  const int gsw  = ((tid & 7) ^ (trow & 7)) * 8;
  const u16* aS00 = A16 + (long)(mt * 256 +   0 +  0 + trow) * 1024 + gsw;
  const u16* aS01 = A16 + (long)(mt * 256 +   0 + 64 + trow) * 1024 + gsw;
  const u16* aS10 = A16 + (long)(mt * 256 + 128 +  0 + trow) * 1024 + gsw;
  const u16* aS11 = A16 + (long)(mt * 256 + 128 + 64 + trow) * 1024 + gsw;
  const u16* bS0  = WT  + (long)(nt * 256 +   0 + trow) * 1024 + gsw;
  const u16* bS1  = WT  + (long)(nt * 256 +  64 + trow) * 1024 + gsw;
  const u16* bS2  = WT  + (long)(nt * 256 + 128 + trow) * 1024 + gsw;
  const u16* bS3  = WT  + (long)(nt * 256 + 192 + trow) * 1024 + gsw;

#define AQOFF(wr2, h, sl) ((((wr2) * 2 + (h)) * 2 + (sl)) * 8192)
#define BOFF(sl)          (65536 + (sl) * 32768)

#define STAGE_ALL(sl, kt)                                                       \
  { __builtin_amdgcn_global_load_lds((const AS1 void*)(bS0 + (kt) * 64),        \
        (AS3 void*)(lds_raw + BOFF(sl) +     0 + w * 1024), 16, 0, 0);          \
    __builtin_amdgcn_global_load_lds((const AS1 void*)(bS1 + (kt) * 64),        \
        (AS3 void*)(lds_raw + BOFF(sl) +  8192 + w * 1024), 16, 0, 0);          \
    __builtin_amdgcn_global_load_lds((const AS1 void*)(bS2 + (kt) * 64),        \
        (AS3 void*)(lds_raw + BOFF(sl) + 16384 + w * 1024), 16, 0, 0);          \
    __builtin_amdgcn_global_load_lds((const AS1 void*)(bS3 + (kt) * 64),        \
        (AS3 void*)(lds_raw + BOFF(sl) + 24576 + w * 1024), 16, 0, 0);          \
    __builtin_amdgcn_global_load_lds((const AS1 void*)(aS00 + (kt) * 64),       \
        (AS3 void*)(lds_raw + AQOFF(0, 0, sl) + w * 1024), 16, 0, 0);           \
    __builtin_amdgcn_global_load_lds((const AS1 void*)(aS10 + (kt) * 64),       \
        (AS3 void*)(lds_raw + AQOFF(1, 0, sl) + w * 1024), 16, 0, 0);           \
    __builtin_amdgcn_global_load_lds((const AS1 void*)(aS01 + (kt) * 64),       \
        (AS3 void*)(lds_raw + AQOFF(0, 1, sl) + w * 1024), 16, 0, 0);           \
    __builtin_amdgcn_global_load_lds((const AS1 void*)(aS11 + (kt) * 64),       \
        (AS3 void*)(lds_raw + AQOFF(1, 1, sl) + w * 1024), 16, 0, 0); }

  int aoff0[4], aoff1[4], boff0[4], boff1[4];
#pragma unroll
  for (int la = 0; la < 4; ++la) {
    int rq = la * 16 + ln;
    aoff0[la] = rq * 128 + (((0 * 4 + lg) ^ (ln & 7)) * 16);
    aoff1[la] = rq * 128 + (((1 * 4 + lg) ^ (ln & 7)) * 16);
  }
#pragma unroll
  for (int j = 0; j < 4; ++j) {
    int nl = wc * 64 + j * 16 + ln;
    boff0[j] = nl * 128 + (((0 * 4 + lg) ^ (ln & 7)) * 16);
    boff1[j] = nl * 128 + (((1 * 4 + lg) ^ (ln & 7)) * 16);
  }

  f32x4 acc[8][4] = {};

#define MFMA_SET(IB, BF)                                                        \
    _Pragma("unroll")                                                           \
    for (int la = 0; la < 4; ++la)                                              \
      _Pragma("unroll")                                                         \
      for (int j = 0; j < 4; ++j)                                               \
        acc[(IB) + la][j] = __builtin_amdgcn_mfma_f32_16x16x32_bf16(            \
            afv[la], BF[j], acc[(IB) + la][j], 0, 0, 0);

#define KITER(T, STG)                                                           \
  {                                                                             \
    const int slot = (T) & 1, nslot = slot ^ 1;                                 \
    const char* aqb0 = lds_raw + AQOFF(wr, 0, slot);                            \
    const char* aqb1 = lds_raw + AQOFF(wr, 1, slot);                            \
    const char* bqb  = lds_raw + BOFF(slot);                                    \
    s16x8 bfr[4], afv[4];                                                       \
    if (STG) STAGE_ALL(nslot, (T) + 1);                                         \
    /* cluster 1: low x ks0 — compiler-managed waitcnts from here on */         \
    _Pragma("unroll")                                                           \
    for (int la = 0; la < 4; ++la) afv[la] = *(const s16x8*)(aqb0 + aoff0[la]); \
    _Pragma("unroll")                                                           \
    for (int j = 0; j < 4; ++j) bfr[j] = *(const s16x8*)(bqb + boff0[j]);       \
    MFMA_SET(0, bfr)                                                            \
    /* cluster 2: up x ks0 */                                                   \
    _Pragma("unroll")                                                           \
    for (int la = 0; la < 4; ++la) afv[la] = *(const s16x8*)(aqb1 + aoff0[la]); \
    MFMA_SET(4, bfr)                                                            \
    /* cluster 3: low x ks1 */                                                  \
    _Pragma("unroll")                                                           \
    for (int la = 0; la < 4; ++la) afv[la] = *(const s16x8*)(aqb0 + aoff1[la]); \
    _Pragma("unroll")                                                           \
    for (int j = 0; j < 4; ++j) bfr[j] = *(const s16x8*)(bqb + boff1[j]);       \
    MFMA_SET(0, bfr)                                                            \
    /* cluster 4: up x ks1 */                                                   \
    _Pragma("unroll")                                                           \
    for (int la = 0; la < 4; ++la) afv[la] = *(const s16x8*)(aqb1 + aoff1[la]); \
    MFMA_SET(4, bfr)                                                            \
    __syncthreads();  /* one drain+barrier per K-tile */                        \
  }

  STAGE_ALL(0, 0);
  __syncthreads();

  for (int t = 0; t < 15; ++t)
    KITER(t, 1)
  KITER(15, 0)

#undef KITER
#undef MFMA_SET
#undef STAGE_ALL
#undef AQOFF
#undef BOFF

  // ================= epilogue (spill-proof, LDS-staged, fast celu) =========
  u16*   Csh = (u16*)lds_raw;                 // [256][264] padded pitch
  float* red = (float*)(lds_raw + 135168);    // [256][4][2]

  float bsv[4];
#pragma unroll
  for (int j = 0; j < 4; ++j) bsv[j] = bias[nt * 256 + wc * 64 + j * 16 + ln];

#pragma unroll
  for (int i = 0; i < 8; ++i) {
    float s1[4] = {0.f, 0.f, 0.f, 0.f}, s2[4] = {0.f, 0.f, 0.f, 0.f};
#pragma unroll
    for (int j = 0; j < 4; ++j) {
#pragma unroll
      for (int r = 0; r < 4; ++r) {
        float c = celu_f(acc[i][j][r] + bsv[j]);
        s1[r] += c; s2[r] += c * c;
        int rl = wr * 128 + i * 16 + 4 * lg + r;
        Csh[rl * 264 + wc * 64 + j * 16 + ln] = f2bf(c);
      }
    }
#pragma unroll
    for (int r = 0; r < 4; ++r) {
#pragma unroll
      for (int m = 1; m < 16; m <<= 1) {
        s1[r] += __shfl_xor(s1[r], m); s2[r] += __shfl_xor(s2[r], m);
      }
      if (ln == 0) {
        int rl = wr * 128 + i * 16 + 4 * lg + r;
        red[(rl * 4 + wc) * 2 + 0] = s1[r];
        red[(rl * 4 + wc) * 2 + 1] = s2[r];
      }
    }
  }
  __syncthreads();

  const int rsub = tid >> 5;
  const int cseg = (tid & 31) * 8;
  const int g2   = (cseg >> 7) * 2;
#pragma unroll 4
  for (int s = 0; s < 16; ++s) {
    int row_l = s * 16 + rsub;
    float s1t = red[(row_l * 4 + g2) * 2 + 0] + red[(row_l * 4 + g2 + 1) * 2 + 0];
    float s2t = red[(row_l * 4 + g2) * 2 + 1] + red[(row_l * 4 + g2 + 1) * 2 + 1];
    float mean = s1t * 0.0078125f;
    float var  = s2t * 0.0078125f - mean * mean;
    float inv  = rsqrtf(var + 1e-5f);
    u16x8 cv = *(const u16x8*)(Csh + row_l * 264 + cseg);
    int col0 = nt * 256 + cseg;
    f32x4 g0 = *(const f32x4*)(gamma + col0);
    f32x4 g1 = *(const f32x4*)(gamma + col0 + 4);
    f32x4 b0 = *(const f32x4*)(beta + col0);
    f32x4 b1 = *(const f32x4*)(beta + col0 + 4);
    u16x8 ov;
#pragma unroll
    for (int e = 0; e < 4; ++e) {
      ov[e]     = f2bf((bf2f(cv[e])     - mean) * inv * g0[e] + b0[e]);
      ov[4 + e] = f2bf((bf2f(cv[4 + e]) - mean) * inv * g1[e] + b1[e]);
    }
    *(u16x8*)(Cout + (long)(mt * 256 + row_l) * 1024 + col0) = ov;
  }
}

// ---------------------------------------------------------------------------
// Stage 2: am MFMA + pools + softmax + vectorized PV.  expf -> __expf
// (native v_exp; same libm-tax class as the round-14 celu win).
// ---------------------------------------------------------------------------
__global__ __launch_bounds__(256) void stage2(
    const float* __restrict__ qb, const float* __restrict__ v1b,
    const u16* __restrict__ kbuf, const u16* __restrict__ v2buf,
    const u16* __restrict__ wbT, const float* __restrict__ bb,
    const float* __restrict__ Wl, const float* __restrict__ bl,
    const float* __restrict__ Wl2, const float* __restrict__ bl2,
    const float* __restrict__ mask, float* __restrict__ out)
{
  const int bh = blockIdx.x, b = bh >> 3, h = bh & 7;
  const int tid = threadIdx.x, lane = tid & 63, w = tid >> 6;
  const int lg = lane >> 4, ln = lane & 15;

  __shared__ float s_arr[1024];
  __shared__ float pool_l[4][64];
  __shared__ float poolf[64];
  __shared__ float ach[128];
  __shared__ float psum2[4][128];
  __shared__ float rmsk[4], rmax[4], rsum[4];

  float qv[4][8];
#pragma unroll
  for (int ks = 0; ks < 4; ++ks)
#pragma unroll
    for (int e = 0; e < 8; ++e)
      qv[ks][e] = qb[b * 1024 + h * 128 + ks * 32 + lg * 8 + e];

  s16x8 bfr[4][4];
#pragma unroll
  for (int nj = 0; nj < 4; ++nj)
#pragma unroll
    for (int ks = 0; ks < 4; ++ks)
      bfr[nj][ks] = *(const s16x8*)(&wbT[(nj * 16 + ln) * 128 + ks * 32 + lg * 8]);

  float wlv[4], bbv[4];
#pragma unroll
  for (int nj = 0; nj < 4; ++nj) { wlv[nj] = Wl[nj * 16 + ln]; bbv[nj] = bb[nj * 16 + ln]; }

  float mpart = 0.f;
  for (int m = tid; m < 1024; m += 256) mpart += mask[b * 1024 + m];

  float poolacc[4] = {0.f, 0.f, 0.f, 0.f};

  for (int c = 0; c < 16; ++c) {
    const int m0 = w * 256 + c * 16;
    f32x4 amacc[4] = {};
#pragma unroll
    for (int ks = 0; ks < 4; ++ks) {
      const u16* kp = kbuf + (long)(b * 1024 + m0 + ln) * 1024 + h * 128 + ks * 32 + lg * 8;
      u16x8 kw = *(const u16x8*)kp;
      s16x8 af;
#pragma unroll
      for (int e = 0; e < 8; ++e) af[e] = (short)f2bf(bf2f(kw[e]) * qv[ks][e]);
#pragma unroll
      for (int nj = 0; nj < 4; ++nj)
        amacc[nj] = __builtin_amdgcn_mfma_f32_16x16x32_bf16(af, bfr[nj][ks], amacc[nj], 0, 0, 0);
    }
    float mrow[4];
#pragma unroll
    for (int r = 0; r < 4; ++r) mrow[r] = mask[b * 1024 + m0 + lg * 4 + r];
    float sp[4] = {0.f, 0.f, 0.f, 0.f};
#pragma unroll
    for (int nj = 0; nj < 4; ++nj)
#pragma unroll
      for (int r = 0; r < 4; ++r) {
        float a = fmaxf(amacc[nj][r] + bbv[nj], 0.f);
        poolacc[nj] += a * mrow[r];
        sp[r] += a * wlv[nj];
      }
#pragma unroll
    for (int m = 1; m < 16; m <<= 1)
#pragma unroll
      for (int r = 0; r < 4; ++r) sp[r] += __shfl_xor(sp[r], m);
    if (ln == 0) {
#pragma unroll
      for (int r = 0; r < 4; ++r) s_arr[m0 + lg * 4 + r] = sp[r] + bl[0];
    }
  }
#pragma unroll
  for (int m = 16; m < 64; m <<= 1)
#pragma unroll
    for (int nj = 0; nj < 4; ++nj) poolacc[nj] += __shfl_xor(poolacc[nj], m);
  if (lg == 0) {
#pragma unroll
    for (int nj = 0; nj < 4; ++nj) pool_l[w][nj * 16 + ln] = poolacc[nj];
  }
#pragma unroll
  for (int m = 1; m < 64; m <<= 1) mpart += __shfl_xor(mpart, m);
  if (lane == 0) rmsk[w] = mpart;
  __syncthreads();   // B1
  const float msum = rmsk[0] + rmsk[1] + rmsk[2] + rmsk[3];
  if (tid < 64) poolf[tid] = pool_l[0][tid] + pool_l[1][tid] + pool_l[2][tid] + pool_l[3][tid];
  float lmax = -3.0e38f;
  for (int m = tid; m < 1024; m += 256) {
    float sv = (mask[b * 1024 + m] == 0.f) ? -1.0e9f : s_arr[m];
    s_arr[m] = sv;
    lmax = fmaxf(lmax, sv);
  }
#pragma unroll
  for (int m = 1; m < 64; m <<= 1) lmax = fmaxf(lmax, __shfl_xor(lmax, m));
  if (lane == 0) rmax[w] = lmax;
  __syncthreads();   // B2
  const float gmax = fmaxf(fmaxf(rmax[0], rmax[1]), fmaxf(rmax[2], rmax[3]));
  float lsum = 0.f;
  for (int m = tid; m < 1024; m += 256) {
    float e = __expf(s_arr[m] - gmax);
    s_arr[m] = e;
    lsum += e;
  }
#pragma unroll
  for (int m = 1; m < 64; m <<= 1) lsum += __shfl_xor(lsum, m);
  if (lane == 0) rsum[w] = lsum;
  if (tid < 128) {
    float a = 0.f;
    for (int cc = 0; cc < 64; ++cc) a += poolf[cc] * Wl2[cc * 128 + tid];
    a = a / msum + bl2[tid];
    ach[tid] = 1.f / (1.f + __expf(-a));
  }
  __syncthreads();   // B3
  const float gsum = rsum[0] + rsum[1] + rsum[2] + rsum[3];

  float pacc[8] = {0.f, 0.f, 0.f, 0.f, 0.f, 0.f, 0.f, 0.f};
  const u16* vbase = v2buf + (long)(b * 1024 + w * 256) * 1024 + h * 128 + ln * 8;
#pragma unroll 4
  for (int i = 0; i < 64; ++i) {
    const int mrow = i * 4 + lg;
    u16x8 vv = *(const u16x8*)(vbase + (long)mrow * 1024);
    float s = s_arr[w * 256 + mrow];
#pragma unroll
    for (int e = 0; e < 8; ++e) pacc[e] += s * bf2f(vv[e]);
  }
#pragma unroll
  for (int e = 0; e < 8; ++e) {
    pacc[e] += __shfl_xor(pacc[e], 16);
    pacc[e] += __shfl_xor(pacc[e], 32);
  }
  if (lg == 0) {
    f32x4 p0 = {pacc[0], pacc[1], pacc[2], pacc[3]};
    f32x4 p1 = {pacc[4], pacc[5], pacc[6], pacc[7]};
    *(f32x4*)&psum2[w][ln * 8]     = p0;
    *(f32x4*)&psum2[w][ln * 8 + 4] = p1;
  }
  __syncthreads();   // B4
  if (tid < 128) {
    float pooled = (psum2[0][tid] + psum2[1][tid] + psum2[2][tid] + psum2[3][tid]) / gsum;
    out[b * 1024 + h * 128 + tid] = v1b[b * 1024 + h * 128 + tid] * pooled * ach[tid];
  }
}

// ---------------------------------------------------------------------------
extern "C" void kernel_launch(void* const* d_in, const int* in_sizes, int n_in,
                              void* d_out, int out_size, void* d_ws, size_t ws_size,
                              hipStream_t stream)
{
  (void)in_sizes; (void)n_in; (void)out_size; (void)ws_size;
  const float* query  = (const float*)d_in[0];
  const float* key    = (const float*)d_in[1];
  const float* mask   = (const float*)d_in[2];
  const float* value1 = (const float*)d_in[3];
  const float* value2 = (const float*)d_in[4];
  const float* Wq  = (const float*)d_in[5];
  const float* bq  = (const float*)d_in[6];
  const float* gq  = (const float*)d_in[7];
  const float* gbq = (const float*)d_in[8];
  const float* Wk  = (const float*)d_in[9];
  const float* bk  = (const float*)d_in[10];
  const float* gk  = (const float*)d_in[11];
  const float* gbk = (const float*)d_in[12];
  const float* Wv1  = (const float*)d_in[13];
  const float* bv1  = (const float*)d_in[14];
  const float* gv1  = (const float*)d_in[15];
  const float* gbv1 = (const float*)d_in[16];
  const float* Wv2  = (const float*)d_in[17];
  const float* bv2  = (const float*)d_in[18];
  const float* gv2  = (const float*)d_in[19];
  const float* gbv2 = (const float*)d_in[20];
  const float* Wb  = (const float*)d_in[21];
  const float* bb  = (const float*)d_in[22];
  const float* Wl  = (const float*)d_in[23];
  const float* bl  = (const float*)d_in[24];
  const float* Wl2 = (const float*)d_in[25];
  const float* bl2 = (const float*)d_in[26];
  float* out = (float*)d_out;

  char* ws = (char*)d_ws;
  const long SZ128 = 134217728L;
  u16*   convA  = (u16*)(ws);                 // reused for key then value2
  u16*   k_out  = (u16*)(ws + SZ128);
  u16*   v2_out = (u16*)(ws + 2 * SZ128);
  char*  wbase  = ws + 3 * SZ128;
  u16*   WkT    = (u16*)(wbase);
  u16*   Wv2T   = (u16*)(wbase + 2097152L);
  u16*   WbT    = (u16*)(wbase + 2L * 2097152L);
  float* qbuf   = (float*)(wbase + 2L * 2097152L + 32768L);
  float* v1buf  = (float*)(wbase + 2L * 2097152L + 32768L + 262144L);

  dim3 tb(32, 8);
  transpose3_bf16<<<dim3(32, 65), tb, 0, stream>>>(Wk, WkT, Wv2, Wv2T, Wb, WbT);

  branch_small2<<<1024, 128, 0, stream>>>(query, Wq, bq, gq, gbq, qbuf,
                                          value1, Wv1, bv1, gv1, gbv1, v1buf);

  convert_bf16<<<4096, 256, 0, stream>>>(key, convA, 67108864L);
  gemm256p3<<<1024, 512, 0, stream>>>(convA, WkT, bk, gk, gbk, k_out);

  convert_bf16<<<4096, 256, 0, stream>>>(value2, convA, 67108864L);
  gemm256p3<<<1024, 512, 0, stream>>>(convA, Wv2T, bv2, gv2, gbv2, v2_out);

  stage2<<<512, 256, 0, stream>>>(qbuf, v1buf, k_out, v2_out, WbT,
                                  bb, Wl, bl, Wl2, bl2, mask, out);
}